// Round 3
// baseline (217.029 us; speedup 1.0000x reference)
//
#include <hip/hip_runtime.h>
#include <hip/hip_bf16.h>
#include <cstdint>

typedef __bf16 bf16_t;
typedef bf16_t bf16x8 __attribute__((ext_vector_type(8)));
typedef bf16_t bf16x4 __attribute__((ext_vector_type(4)));
typedef float  f32x4  __attribute__((ext_vector_type(4)));

#define S0 512
#define S1 256
#define S2 128
#define NGRID 128
#define GPTS (NGRID*NGRID)   // 16384

// workspace layout (bytes)
#define WS_BASE  0u          // 16*512 f32            = 32 KB
#define WS_W1P   32768u      // 262144*8 bf16         = 4 MB
#define WS_W2P   4227072u    // 65536*8 bf16          = 1 MB
#define WS_W3P   5275648u    // 4096*8 bf16           = 64 KB
#define WS_BASEC 5341184u    // 16*512 f32 compacted  = 32 KB
#define WS_WXYC  5373952u    // 16*512*2 f32          = 64 KB
#define WS_IDX   5439488u    // 16*512 int            = 32 KB
#define WS_LIN   5472256u    // 16*512 int            = 32 KB
#define WS_F     5505024u    // 16*256*4 f32          = 64 KB
#define WS_CNT   5570560u    // Kc[16] + nlin[16]

__device__ __forceinline__ float tanh_fast(float x) {
  float e = __builtin_amdgcn_exp2f(x * 2.88539008f);   // 2*log2(e)
  return fmaf(-2.0f, __builtin_amdgcn_rcpf(e + 1.0f), 1.0f);
}

// ---------------------------------------------------------------------------
// Launch 1: blocks [0,2048): base[m][o] = W0a·x0 + b0a + b0b  (fp32)
//           blocks [2048,2368): pack W2/W3 into bf16 MFMA B-frag order
// ---------------------------------------------------------------------------
__global__ __launch_bounds__(256) void prep_a(
    const float* __restrict__ x0, const float* __restrict__ W0a,
    const float* __restrict__ b0a, const float* __restrict__ b0b,
    const float* __restrict__ W2, const float* __restrict__ W3,
    float* __restrict__ base, bf16_t* __restrict__ W2p, bf16_t* __restrict__ W3p)
{
  if (blockIdx.x < 2048) {
    int wid = (blockIdx.x << 2) + (threadIdx.x >> 6);   // 0..8191
    int L = threadIdx.x & 63;
    int m = wid >> 9, o = wid & 511;
    const float* wrow = W0a + ((size_t)(m*S0 + o) << 10);
    float acc = 0.f;
#pragma unroll
    for (int i = 0; i < 4; ++i) {
      f32x4 wv = *(const f32x4*)(wrow + i*256 + L*4);
      f32x4 xv = *(const f32x4*)(x0   + i*256 + L*4);
      acc += wv.x*xv.x + wv.y*xv.y + wv.z*xv.z + wv.w*xv.w;
    }
#pragma unroll
    for (int s = 32; s; s >>= 1) acc += __shfl_xor(acc, s, 64);
    if (L == 0) base[m*S0 + o] = acc + b0a[m*S0 + o] + b0b[m*S0 + o];
    return;
  }

  int T = (blockIdx.x - 2048) * 256 + threadIdx.x;  // 81920 total
  const float* src = nullptr;
  bf16_t* dst = nullptr;
  if (T < 65536) {                  // W2: 16m * 8ks * 8nt * 64L
    int L = T & 63, nt = (T >> 6) & 7, ks = (T >> 9) & 7, m = T >> 12;
    int n = nt*16 + (L & 15), k0 = ks*32 + ((L >> 4) & 3)*8;
    src = W2 + (size_t)(m*S2 + n)*S1 + k0;
    dst = W2p + (size_t)T*8;
  } else {                          // W3: 16m * 4ks * 1nt * 64L (N padded to 16)
    int T3 = T - 65536;
    int L = T3 & 63, ks = (T3 >> 6) & 3, m = T3 >> 8;
    int n = L & 15, k0 = ks*32 + ((L >> 4) & 3)*8;
    dst = W3p + (size_t)T3*8;
    if (n < 3) src = W3 + (size_t)(m*3 + n)*S2 + k0;
  }
  bf16x8 v;
  if (src) {
    f32x4 a = *(const f32x4*)src;
    f32x4 b = *(const f32x4*)(src + 4);
    v[0]=(bf16_t)a.x; v[1]=(bf16_t)a.y; v[2]=(bf16_t)a.z; v[3]=(bf16_t)a.w;
    v[4]=(bf16_t)b.x; v[5]=(bf16_t)b.y; v[6]=(bf16_t)b.z; v[7]=(bf16_t)b.w;
  } else {
#pragma unroll
    for (int j = 0; j < 8; ++j) v[j] = (bf16_t)0.f;
  }
  *(bf16x8*)dst = v;
}

// ---------------------------------------------------------------------------
// Launch 2: per-m channel classification over the full grid [-1,1]^2.
//   dead   : base + |wx| + |wy| <= 0  -> relu == 0 everywhere -> drop
//   linear : base - |wx| - |wy| >= 0  -> relu == identity     -> fold (rank-1)
//   active : the rest -> compacted (idx, basec, wxyc) for the MFMA path
// One block per m. Combined 16-bit-field Hillis-Steele scan over 512 flags.
// ---------------------------------------------------------------------------
__global__ __launch_bounds__(256) void classify_k(
    const float* __restrict__ base, const float* __restrict__ W0b,
    float* __restrict__ basec, float* __restrict__ wxyc,
    int* __restrict__ idx, int* __restrict__ lin,
    int* __restrict__ Kc, int* __restrict__ nlin, float* __restrict__ F)
{
  __shared__ int sc[512];
  const int m = blockIdx.x, t = threadIdx.x;
  float b[2], wx[2], wy[2]; int fa[2], fl[2];
#pragma unroll
  for (int h = 0; h < 2; ++h) {
    const int k = t + h*256;
    b[h]  = base[m*S0 + k];
    wx[h] = W0b[(m*S0 + k)*2];
    wy[h] = W0b[(m*S0 + k)*2 + 1];
    const float aw = fabsf(wx[h]) + fabsf(wy[h]);
    const int dead = (b[h] + aw) <= 0.f;
    fl[h] = (!dead) && ((b[h] - aw) >= 0.f);
    fa[h] = (!dead) && (!fl[h]);
    sc[k] = fa[h] | (fl[h] << 16);
  }
  __syncthreads();
  for (int off = 1; off < 512; off <<= 1) {
    int v0 = sc[t], v1 = sc[t+256];
    int u0 = (t >= off) ? sc[t-off] : 0;
    int u1 = (t+256 >= off) ? sc[t+256-off] : 0;
    __syncthreads();
    sc[t] = v0 + u0; sc[t+256] = v1 + u1;
    __syncthreads();
  }
  const int tot = sc[511];
  const int KcM = tot & 0xffff, nlM = tot >> 16;
#pragma unroll
  for (int h = 0; h < 2; ++h) {
    const int k = t + h*256;
    const int incl = sc[k];
    if (fa[h]) {
      const int p = (incl & 0xffff) - 1;
      idx[m*S0 + p] = k;
      basec[m*S0 + p] = b[h];
      wxyc[m*S0*2 + 2*p]     = wx[h];
      wxyc[m*S0*2 + 2*p + 1] = wy[h];
    } else if (fl[h]) {
      lin[m*S0 + ((incl >> 16) - 1)] = k;
    }
  }
  // zero tails (slots >= KcM are disjoint from the active writes above)
  for (int s = t; s < 512; s += 256) {
    if (s >= KcM) {
      idx[m*S0 + s] = 0;
      basec[m*S0 + s] = 0.f;
      wxyc[m*S0*2 + 2*s] = 0.f;
      wxyc[m*S0*2 + 2*s + 1] = 0.f;
    }
  }
  for (int i = t; i < 1024; i += 256) F[m*1024 + i] = 0.f;  // fold accumulators
  if (t == 0) { Kc[m] = KcM; nlin[m] = nlM; }
}

// ---------------------------------------------------------------------------
// Launch 3: blocks [0,1024): gather-pack W1 columns idx[m][k'] into B-frag
//           order. Chunks >= nks are ZERO-FILLED (safe over-read).
//           blocks [1024,1280): fold linear channels: F[m][n] =
//             sum_lin W1[n,k] * (base_k, wx_k, wy_k)  (16 k-slices, atomicAdd)
// ---------------------------------------------------------------------------
__global__ __launch_bounds__(256) void prep_b(
    const float* __restrict__ W1, const float* __restrict__ base,
    const float* __restrict__ W0b,
    const int* __restrict__ idx, const int* __restrict__ lin,
    const int* __restrict__ Kc, const int* __restrict__ nlin,
    bf16_t* __restrict__ W1p, float* __restrict__ F)
{
  if (blockIdx.x < 1024) {
    const int T = blockIdx.x*256 + threadIdx.x;   // < 262144
    const int L = T & 63, nt = (T >> 6) & 15, ks = (T >> 10) & 15, m = T >> 14;
    const int KcM = Kc[m];
    const int n = nt*16 + (L & 15), kb = ks*32 + ((L >> 4) & 3)*8;
    const float* wrow = W1 + (size_t)(m*S1 + n)*S0;
    const int* ip = idx + m*S0 + kb;
    bf16x8 v;
#pragma unroll
    for (int j = 0; j < 8; ++j)
      v[j] = (kb + j < KcM) ? (bf16_t)wrow[ip[j]] : (bf16_t)0.f;
    *(bf16x8*)(W1p + (size_t)T*8) = v;
  } else {
    const int b2 = blockIdx.x - 1024;              // 0..255
    const int m = b2 >> 4, s = b2 & 15, n = threadIdx.x;
    const int nl = nlin[m];
    float a0 = 0.f, ax = 0.f, ay = 0.f;
    const float* wrow = W1 + (size_t)(m*S1 + n)*S0;
    for (int j = s; j < nl; j += 16) {
      const int k = lin[m*S0 + j];
      const float w = wrow[k];
      a0 = fmaf(w, base[m*S0 + k], a0);
      ax = fmaf(w, W0b[(m*S0 + k)*2], ax);
      ay = fmaf(w, W0b[(m*S0 + k)*2 + 1], ay);
    }
    float* fp = F + ((size_t)m*S1 + n)*4;
    atomicAdd(fp + 0, a0);
    atomicAdd(fp + 1, a0*0.f + ax);
    atomicAdd(fp + 2, ay);
  }
}

// ---------------------------------------------------------------------------
// L1 K-loop, static trip count NKS, LDS-SHARED A-fragments:
// wave w generates ONLY its own mt=w row-block (8 elems/lane: 2 fma+max+cvt),
// stores 1 KB to a double-buffered staging area (canonical per-lane-16B
// layout, conflict-free b128), one barrier, then every wave ds_read_b128's
// all 4 fragments. 4x less activation VALU than redundant-per-wave gen.
// Element->fragment mapping is identical by construction: writer lane
// (quad,lrow) of wave w produces af[mt=w][j] for reader lane (quad,lrow).
// Staging aliases the head of sA1 (dead during the K-loop); caller barriers
// before the L1 epilogue writes sA1.
// ---------------------------------------------------------------------------
template<int NKS>
__device__ __forceinline__ void l1_compute(
    const bf16_t* __restrict__ bp1, const float* __restrict__ bc,
    const float* __restrict__ wc, bf16_t* sStg,
    const int w, const int L, const int quad, const float yv,
    const float xrw, f32x4 (&acc1)[4][4])
{
  bf16x8 Bc[4];
#pragma unroll
  for (int n = 0; n < 4; ++n) Bc[n] = *(const bf16x8*)(bp1 + (size_t)n*512);

#pragma unroll 2
  for (int ks = 0; ks < NKS; ++ks) {
    const int kk = ks*32 + quad*8;

    bf16x8 Bn[4];
    if (ks + 1 < NKS) {
#pragma unroll
      for (int n = 0; n < 4; ++n)
        Bn[n] = *(const bf16x8*)(bp1 + (size_t)(ks+1)*8192 + (size_t)n*512);
    }

    // generate this wave's 8 elements: row = w*16+lrow (x=xrw), k = kk..kk+7
    f32x4 cA  = *(const f32x4*)(bc + kk);
    f32x4 cB  = *(const f32x4*)(bc + kk + 4);
    f32x4 wv0 = *(const f32x4*)(wc + kk*2);
    f32x4 wv1 = *(const f32x4*)(wc + kk*2 + 4);
    f32x4 wv2 = *(const f32x4*)(wc + kk*2 + 8);
    f32x4 wv3 = *(const f32x4*)(wc + kk*2 + 12);
    bf16x8 g;
    g[0] = (bf16_t)fmaxf(fmaf(wv0.x, xrw, fmaf(wv0.y, yv, cA.x)), 0.f);
    g[1] = (bf16_t)fmaxf(fmaf(wv0.z, xrw, fmaf(wv0.w, yv, cA.y)), 0.f);
    g[2] = (bf16_t)fmaxf(fmaf(wv1.x, xrw, fmaf(wv1.y, yv, cA.z)), 0.f);
    g[3] = (bf16_t)fmaxf(fmaf(wv1.z, xrw, fmaf(wv1.w, yv, cA.w)), 0.f);
    g[4] = (bf16_t)fmaxf(fmaf(wv2.x, xrw, fmaf(wv2.y, yv, cB.x)), 0.f);
    g[5] = (bf16_t)fmaxf(fmaf(wv2.z, xrw, fmaf(wv2.w, yv, cB.y)), 0.f);
    g[6] = (bf16_t)fmaxf(fmaf(wv3.x, xrw, fmaf(wv3.y, yv, cB.z)), 0.f);
    g[7] = (bf16_t)fmaxf(fmaf(wv3.z, xrw, fmaf(wv3.w, yv, cB.w)), 0.f);

    bf16_t* stg = sStg + (ks & 1)*2048;          // 2 x 4 KB buffers
    *(bf16x8*)(stg + ((w << 6) + L)*8) = g;
    __syncthreads();                              // staging visible to all

#pragma unroll
    for (int mt = 0; mt < 4; ++mt) {
      bf16x8 af = *(const bf16x8*)(stg + ((mt << 6) + L)*8);
#pragma unroll
      for (int n = 0; n < 4; ++n)
        acc1[mt][n] = __builtin_amdgcn_mfma_f32_16x16x32_bf16(Bc[n], af, acc1[mt][n], 0, 0, 0);
    }
    if (ks + 1 < NKS) {
#pragma unroll
      for (int n = 0; n < 4; ++n) Bc[n] = Bn[n];
    }
  }
}

// ---------------------------------------------------------------------------
// Fused MLP. One WG = (m = bid>>8, 64-row grid tile = bid&255); m-major so all
// concurrent WGs share 2-3 m's -> packed weights L2-resident per XCD.
// L1 runs only the COMPACTED active channels (nks = ceil(Kc/32) K-chunks,
// static trip count via switch, LDS-shared A-frags); linear channels enter via
// the rank-1 fold F0 + Fx*x + Fy*y in the epilogue. MFMA operands swapped
// (B,A) -> D = C^T. Frag layouts (A and B identical): row/col = lane&15,
// k = (lane>>4)*8+j;  C/D: col = lane&15, row = quad*4+p.
// ---------------------------------------------------------------------------
__global__ __launch_bounds__(256, 4) void fused_mlp_k(
    const float* __restrict__ basec, const float* __restrict__ wxyc,
    const float* __restrict__ F, const int* __restrict__ Kc,
    const bf16_t* __restrict__ W1p, const bf16_t* __restrict__ W2p,
    const bf16_t* __restrict__ W3p,
    const float* __restrict__ b1, const float* __restrict__ b2,
    const float* __restrict__ b3, float* __restrict__ out)
{
  __shared__ __align__(16) bf16_t sA1[64*264];  // 33792 B; head doubles as L1
                                                // A-staging; reused as h2 later

  const int bid  = blockIdx.x;
  const int m    = bid >> 8;            // m-major: L2-resident weights
  const int tile = bid & 255;
  const int g0   = tile * 64;

  const int tid  = threadIdx.x;
  const int w    = tid >> 6, L = tid & 63;
  const int quad = L >> 4, lrow = L & 15;

  const float step = 2.0f / 127.0f;
  const float yv  = -1.0f + (float)(tile >> 1) * step;
  const float xv0 = -1.0f + (float)(((tile & 1) << 6) + lrow) * step;  // mt=0 row
  const float xrw = xv0 + (float)(w*16)*step;   // this wave's generated row

  const float* bc = basec + m*S0;
  const float* wc = wxyc + m*(S0*2);
  const int nks = (Kc[m] + 31) >> 5;    // compacted K-chunks (~10 of 16)

  f32x4 zero = {0.f, 0.f, 0.f, 0.f};
  f32x4 acc1[4][4];
#pragma unroll
  for (int a = 0; a < 4; ++a)
#pragma unroll
    for (int b = 0; b < 4; ++b) acc1[a][b] = zero;

  // ---------------- Layer 1: static-trip compacted K-loop ----------------
  const bf16_t* bp1 = W1p + (((size_t)(m*16)*16 + w*4)*64 + L)*8;
#define L1_CASE(NN) case NN: l1_compute<NN>(bp1, bc, wc, sA1, w, L, quad, yv, xrw, acc1); break;
  switch (nks) {
    L1_CASE(16) L1_CASE(15) L1_CASE(14) L1_CASE(13)
    L1_CASE(12) L1_CASE(11) L1_CASE(10) L1_CASE(9)
    L1_CASE(8)  L1_CASE(7)  L1_CASE(6)  L1_CASE(5)
    L1_CASE(4)  L1_CASE(3)  L1_CASE(2)  L1_CASE(1)
    default: break;   // nks == 0: all channels dead/linear, acc stays 0
  }
#undef L1_CASE
  __syncthreads();   // staging reads done before epilogue overwrites sA1

  // L1 epilogue: add bias + linear-channel fold (F0 + Fx*x + Fy*y), relu,
  // D^T -> thread holds 4 contiguous cols -> packed b64 stores
#pragma unroll
  for (int nb = 0; nb < 4; ++nb) {
    const int col = w*64 + nb*16 + quad*4;
    f32x4 bb = *(const f32x4*)(b1 + m*S1 + col);
    float cterm[4], fx[4];
#pragma unroll
    for (int p = 0; p < 4; ++p) {
      f32x4 Fv = *(const f32x4*)(F + ((size_t)m*S1 + col + p)*4);
      cterm[p] = fmaf(Fv.z, yv, bb[p] + Fv.x);   // b1 + F0 + Fy*y
      fx[p] = Fv.y;
    }
#pragma unroll
    for (int mt = 0; mt < 4; ++mt) {
      const int row = mt*16 + lrow;
      const float xr = xv0 + (float)(mt*16)*step;
      bf16x4 v;
#pragma unroll
      for (int p = 0; p < 4; ++p)
        v[p] = (bf16_t)fmaxf(acc1[mt][nb][p] + fmaf(fx[p], xr, cterm[p]), 0.f);
      *(bf16x4*)(&sA1[row*264 + col]) = v;
    }
  }
  __syncthreads();

  // ---------------- Layer 2: K=256, 8 chunks, barrier-free loop ----------------
  f32x4 acc2[4][2];
#pragma unroll
  for (int a = 0; a < 4; ++a) { acc2[a][0] = zero; acc2[a][1] = zero; }
  const bf16_t* bp2 = W2p + (((size_t)(m*8)*8 + w*2)*64 + L)*8;
#pragma unroll 2
  for (int ks = 0; ks < 8; ++ks) {
    const int k2 = ks*32 + quad*8;
    bf16x8 af[4];
#pragma unroll
    for (int mt = 0; mt < 4; ++mt)
      af[mt] = *(const bf16x8*)(&sA1[(mt*16 + lrow)*264 + k2]);
    bf16x8 b0f = *(const bf16x8*)(bp2 + (size_t)ks*4096);
    bf16x8 b1f = *(const bf16x8*)(bp2 + (size_t)ks*4096 + 512);
#pragma unroll
    for (int mt = 0; mt < 4; ++mt)
      acc2[mt][0] = __builtin_amdgcn_mfma_f32_16x16x32_bf16(b0f, af[mt], acc2[mt][0], 0, 0, 0);
#pragma unroll
    for (int mt = 0; mt < 4; ++mt)
      acc2[mt][1] = __builtin_amdgcn_mfma_f32_16x16x32_bf16(b1f, af[mt], acc2[mt][1], 0, 0, 0);
  }
  __syncthreads();   // all sA1 reads done before aliased h2 writes

  // L2 epilogue: h2 -> sH2 [64][136], packed b64 stores
  bf16_t* sH2 = sA1;
#pragma unroll
  for (int nb = 0; nb < 2; ++nb) {
    const int col = w*32 + nb*16 + quad*4;
    f32x4 bb = *(const f32x4*)(b2 + m*S2 + col);
#pragma unroll
    for (int mt = 0; mt < 4; ++mt) {
      const int row = mt*16 + lrow;
      bf16x4 v;
#pragma unroll
      for (int p = 0; p < 4; ++p)
        v[p] = (bf16_t)fmaxf(acc2[mt][nb][p] + bb[p], 0.f);
      *(bf16x4*)(&sH2[row*136 + col]) = v;
    }
  }
  __syncthreads();

  // ---------------- Layer 3: K=128, N padded to 16 ----------------
  f32x4 acc3 = zero;
#pragma unroll
  for (int ks = 0; ks < 4; ++ks) {
    bf16x8 af  = *(const bf16x8*)(&sH2[(w*16 + lrow)*136 + ks*32 + quad*8]);
    bf16x8 bfr = *(const bf16x8*)(W3p + (((size_t)m*4 + ks)*64 + L)*8);
    acc3 = __builtin_amdgcn_mfma_f32_16x16x32_bf16(bfr, af, acc3, 0, 0, 0);
  }
  if (quad == 0) {   // thread holds channels p=0..3 for grid row w*16+lrow
    const size_t o = ((size_t)m*GPTS + g0 + w*16 + lrow)*3;
    out[o + 0] = tanh_fast(acc3[0] + b3[m*3 + 0]);
    out[o + 1] = tanh_fast(acc3[1] + b3[m*3 + 1]);
    out[o + 2] = tanh_fast(acc3[2] + b3[m*3 + 2]);
  }
}

// ---------------------------------------------------------------------------
extern "C" void kernel_launch(void* const* d_in, const int* in_sizes, int n_in,
                              void* d_out, int out_size, void* d_ws, size_t ws_size,
                              hipStream_t stream) {
  const float* x0  = (const float*)d_in[0];
  const float* W0a = (const float*)d_in[1];
  const float* b0a = (const float*)d_in[2];
  const float* W0b = (const float*)d_in[3];
  const float* b0b = (const float*)d_in[4];
  const float* W1  = (const float*)d_in[5];
  const float* b1  = (const float*)d_in[6];
  const float* W2  = (const float*)d_in[7];
  const float* b2  = (const float*)d_in[8];
  const float* W3  = (const float*)d_in[9];
  const float* b3  = (const float*)d_in[10];

  char* ws = (char*)d_ws;
  float*  base  = (float*)(ws + WS_BASE);
  bf16_t* W1p   = (bf16_t*)(ws + WS_W1P);
  bf16_t* W2p   = (bf16_t*)(ws + WS_W2P);
  bf16_t* W3p   = (bf16_t*)(ws + WS_W3P);
  float*  basec = (float*)(ws + WS_BASEC);
  float*  wxyc  = (float*)(ws + WS_WXYC);
  int*    idx   = (int*)(ws + WS_IDX);
  int*    lin   = (int*)(ws + WS_LIN);
  float*  F     = (float*)(ws + WS_F);
  int*    Kc    = (int*)(ws + WS_CNT);
  int*    nlin  = (int*)(ws + WS_CNT + 64);
  float*  out   = (float*)d_out;

  prep_a<<<2368, 256, 0, stream>>>(x0, W0a, b0a, b0b, W2, W3, base, W2p, W3p);
  classify_k<<<16, 256, 0, stream>>>(base, W0b, basec, wxyc, idx, lin, Kc, nlin, F);
  prep_b<<<1280, 256, 0, stream>>>(W1, base, W0b, idx, lin, Kc, nlin, W1p, F);
  fused_mlp_k<<<4096, 256, 0, stream>>>(basec, wxyc, F, Kc, W1p, W2p, W3p, b1, b2, b3, out);
}

// Round 4
// 203.935 us; speedup vs baseline: 1.0642x; 1.0642x over previous
//
#include <hip/hip_runtime.h>
#include <hip/hip_bf16.h>
#include <cstdint>

typedef __bf16 bf16_t;
typedef bf16_t bf16x8 __attribute__((ext_vector_type(8)));
typedef bf16_t bf16x4 __attribute__((ext_vector_type(4)));
typedef float  f32x4  __attribute__((ext_vector_type(4)));

#define S0 512
#define S1 256
#define S2 128
#define NGRID 128
#define GPTS (NGRID*NGRID)   // 16384

// workspace layout (bytes)
#define WS_BASE  0u          // 16*512 f32            = 32 KB
#define WS_W1P   32768u      // 262144*8 bf16         = 4 MB
#define WS_W2P   4227072u    // 65536*8 bf16          = 1 MB
#define WS_W3P   5275648u    // 4096*8 bf16           = 64 KB
#define WS_BASEC 5341184u    // 16*512 f32 compacted  = 32 KB
#define WS_WXYC  5373952u    // 16*512*2 f32          = 64 KB
#define WS_IDX   5439488u    // 16*512 int            = 32 KB
#define WS_LIN   5472256u    // 16*512 int            = 32 KB
#define WS_F     5505024u    // 16*256*4 f32          = 64 KB
#define WS_CNT   5570560u    // Kc[16] + nlin[16]

__device__ __forceinline__ float tanh_fast(float x) {
  float e = __builtin_amdgcn_exp2f(x * 2.88539008f);   // 2*log2(e)
  return fmaf(-2.0f, __builtin_amdgcn_rcpf(e + 1.0f), 1.0f);
}

// ---------------------------------------------------------------------------
// Launch 1: blocks [0,2048): base[m][o] = W0a·x0 + b0a + b0b  (fp32)
//           blocks [2048,2368): pack W2/W3 into bf16 MFMA B-frag order
// ---------------------------------------------------------------------------
__global__ __launch_bounds__(256) void prep_a(
    const float* __restrict__ x0, const float* __restrict__ W0a,
    const float* __restrict__ b0a, const float* __restrict__ b0b,
    const float* __restrict__ W2, const float* __restrict__ W3,
    float* __restrict__ base, bf16_t* __restrict__ W2p, bf16_t* __restrict__ W3p)
{
  if (blockIdx.x < 2048) {
    int wid = (blockIdx.x << 2) + (threadIdx.x >> 6);   // 0..8191
    int L = threadIdx.x & 63;
    int m = wid >> 9, o = wid & 511;
    const float* wrow = W0a + ((size_t)(m*S0 + o) << 10);
    float acc = 0.f;
#pragma unroll
    for (int i = 0; i < 4; ++i) {
      f32x4 wv = *(const f32x4*)(wrow + i*256 + L*4);
      f32x4 xv = *(const f32x4*)(x0   + i*256 + L*4);
      acc += wv.x*xv.x + wv.y*xv.y + wv.z*xv.z + wv.w*xv.w;
    }
#pragma unroll
    for (int s = 32; s; s >>= 1) acc += __shfl_xor(acc, s, 64);
    if (L == 0) base[m*S0 + o] = acc + b0a[m*S0 + o] + b0b[m*S0 + o];
    return;
  }

  int T = (blockIdx.x - 2048) * 256 + threadIdx.x;  // 81920 total
  const float* src = nullptr;
  bf16_t* dst = nullptr;
  if (T < 65536) {                  // W2: 16m * 8ks * 8nt * 64L
    int L = T & 63, nt = (T >> 6) & 7, ks = (T >> 9) & 7, m = T >> 12;
    int n = nt*16 + (L & 15), k0 = ks*32 + ((L >> 4) & 3)*8;
    src = W2 + (size_t)(m*S2 + n)*S1 + k0;
    dst = W2p + (size_t)T*8;
  } else {                          // W3: 16m * 4ks * 1nt * 64L (N padded to 16)
    int T3 = T - 65536;
    int L = T3 & 63, ks = (T3 >> 6) & 3, m = T3 >> 8;
    int n = L & 15, k0 = ks*32 + ((L >> 4) & 3)*8;
    dst = W3p + (size_t)T3*8;
    if (n < 3) src = W3 + (size_t)(m*3 + n)*S2 + k0;
  }
  bf16x8 v;
  if (src) {
    f32x4 a = *(const f32x4*)src;
    f32x4 b = *(const f32x4*)(src + 4);
    v[0]=(bf16_t)a.x; v[1]=(bf16_t)a.y; v[2]=(bf16_t)a.z; v[3]=(bf16_t)a.w;
    v[4]=(bf16_t)b.x; v[5]=(bf16_t)b.y; v[6]=(bf16_t)b.z; v[7]=(bf16_t)b.w;
  } else {
#pragma unroll
    for (int j = 0; j < 8; ++j) v[j] = (bf16_t)0.f;
  }
  *(bf16x8*)dst = v;
}

// ---------------------------------------------------------------------------
// Launch 2: per-m channel classification over the full grid [-1,1]^2.
//   dead   : base + |wx| + |wy| <= 0  -> relu == 0 everywhere -> drop
//   linear : base - |wx| - |wy| >= 0  -> relu == identity     -> fold (rank-1)
//   active : the rest -> compacted (idx, basec, wxyc) for the MFMA path
// One block per m. Combined 16-bit-field Hillis-Steele scan over 512 flags.
// ---------------------------------------------------------------------------
__global__ __launch_bounds__(256) void classify_k(
    const float* __restrict__ base, const float* __restrict__ W0b,
    float* __restrict__ basec, float* __restrict__ wxyc,
    int* __restrict__ idx, int* __restrict__ lin,
    int* __restrict__ Kc, int* __restrict__ nlin, float* __restrict__ F)
{
  __shared__ int sc[512];
  const int m = blockIdx.x, t = threadIdx.x;
  float b[2], wx[2], wy[2]; int fa[2], fl[2];
#pragma unroll
  for (int h = 0; h < 2; ++h) {
    const int k = t + h*256;
    b[h]  = base[m*S0 + k];
    wx[h] = W0b[(m*S0 + k)*2];
    wy[h] = W0b[(m*S0 + k)*2 + 1];
    const float aw = fabsf(wx[h]) + fabsf(wy[h]);
    const int dead = (b[h] + aw) <= 0.f;
    fl[h] = (!dead) && ((b[h] - aw) >= 0.f);
    fa[h] = (!dead) && (!fl[h]);
    sc[k] = fa[h] | (fl[h] << 16);
  }
  __syncthreads();
  for (int off = 1; off < 512; off <<= 1) {
    int v0 = sc[t], v1 = sc[t+256];
    int u0 = (t >= off) ? sc[t-off] : 0;
    int u1 = (t+256 >= off) ? sc[t+256-off] : 0;
    __syncthreads();
    sc[t] = v0 + u0; sc[t+256] = v1 + u1;
    __syncthreads();
  }
  const int tot = sc[511];
  const int KcM = tot & 0xffff, nlM = tot >> 16;
#pragma unroll
  for (int h = 0; h < 2; ++h) {
    const int k = t + h*256;
    const int incl = sc[k];
    if (fa[h]) {
      const int p = (incl & 0xffff) - 1;
      idx[m*S0 + p] = k;
      basec[m*S0 + p] = b[h];
      wxyc[m*S0*2 + 2*p]     = wx[h];
      wxyc[m*S0*2 + 2*p + 1] = wy[h];
    } else if (fl[h]) {
      lin[m*S0 + ((incl >> 16) - 1)] = k;
    }
  }
  // zero tails (slots >= KcM are disjoint from the active writes above)
  for (int s = t; s < 512; s += 256) {
    if (s >= KcM) {
      idx[m*S0 + s] = 0;
      basec[m*S0 + s] = 0.f;
      wxyc[m*S0*2 + 2*s] = 0.f;
      wxyc[m*S0*2 + 2*s + 1] = 0.f;
    }
  }
  for (int i = t; i < 1024; i += 256) F[m*1024 + i] = 0.f;  // fold accumulators
  if (t == 0) { Kc[m] = KcM; nlin[m] = nlM; }
}

// ---------------------------------------------------------------------------
// Launch 3: blocks [0,1024): gather-pack W1 columns idx[m][k'] into B-frag
//           order. Chunks >= nks are ZERO-FILLED (safe over-read).
//           blocks [1024,1280): fold linear channels: F[m][n] =
//             sum_lin W1[n,k] * (base_k, wx_k, wy_k)  (16 k-slices, atomicAdd)
// ---------------------------------------------------------------------------
__global__ __launch_bounds__(256) void prep_b(
    const float* __restrict__ W1, const float* __restrict__ base,
    const float* __restrict__ W0b,
    const int* __restrict__ idx, const int* __restrict__ lin,
    const int* __restrict__ Kc, const int* __restrict__ nlin,
    bf16_t* __restrict__ W1p, float* __restrict__ F)
{
  if (blockIdx.x < 1024) {
    const int T = blockIdx.x*256 + threadIdx.x;   // < 262144
    const int L = T & 63, nt = (T >> 6) & 15, ks = (T >> 10) & 15, m = T >> 14;
    const int KcM = Kc[m];
    const int n = nt*16 + (L & 15), kb = ks*32 + ((L >> 4) & 3)*8;
    const float* wrow = W1 + (size_t)(m*S1 + n)*S0;
    const int* ip = idx + m*S0 + kb;
    bf16x8 v;
#pragma unroll
    for (int j = 0; j < 8; ++j)
      v[j] = (kb + j < KcM) ? (bf16_t)wrow[ip[j]] : (bf16_t)0.f;
    *(bf16x8*)(W1p + (size_t)T*8) = v;
  } else {
    const int b2 = blockIdx.x - 1024;              // 0..255
    const int m = b2 >> 4, s = b2 & 15, n = threadIdx.x;
    const int nl = nlin[m];
    float a0 = 0.f, ax = 0.f, ay = 0.f;
    const float* wrow = W1 + (size_t)(m*S1 + n)*S0;
    for (int j = s; j < nl; j += 16) {
      const int k = lin[m*S0 + j];
      const float w = wrow[k];
      a0 = fmaf(w, base[m*S0 + k], a0);
      ax = fmaf(w, W0b[(m*S0 + k)*2], ax);
      ay = fmaf(w, W0b[(m*S0 + k)*2 + 1], ay);
    }
    float* fp = F + ((size_t)m*S1 + n)*4;
    atomicAdd(fp + 0, a0);
    atomicAdd(fp + 1, ax);
    atomicAdd(fp + 2, ay);
  }
}

// ---------------------------------------------------------------------------
// L1 K-loop, static trip count NKS, LDS-SHARED A-fragments:
// wave w generates ONLY its own mt=w row-block (8 elems/lane: 2 fma+max+cvt),
// stores 1 KB to a double-buffered staging area (canonical per-lane-16B
// layout, conflict-free b128), one barrier, then every wave ds_read_b128's
// all 4 fragments. 4x less activation VALU than redundant-per-wave gen.
// Element->fragment mapping is identical by construction: writer lane
// (quad,lrow) of wave w produces af[mt=w][j] for reader lane (quad,lrow).
// Staging aliases the head of sA1 (dead during the K-loop); caller barriers
// before the L1 epilogue writes sA1.
// ---------------------------------------------------------------------------
template<int NKS>
__device__ __forceinline__ void l1_compute(
    const bf16_t* __restrict__ bp1, const float* __restrict__ bc,
    const float* __restrict__ wc, bf16_t* sStg,
    const int w, const int L, const int quad, const float yv,
    const float xrw, f32x4 (&acc1)[4][4])
{
  bf16x8 Bc[4];
#pragma unroll
  for (int n = 0; n < 4; ++n) Bc[n] = *(const bf16x8*)(bp1 + (size_t)n*512);

#pragma unroll 2
  for (int ks = 0; ks < NKS; ++ks) {
    const int kk = ks*32 + quad*8;

    bf16x8 Bn[4];
    if (ks + 1 < NKS) {
#pragma unroll
      for (int n = 0; n < 4; ++n)
        Bn[n] = *(const bf16x8*)(bp1 + (size_t)(ks+1)*8192 + (size_t)n*512);
    }

    // generate this wave's 8 elements: row = w*16+lrow (x=xrw), k = kk..kk+7
    f32x4 cA  = *(const f32x4*)(bc + kk);
    f32x4 cB  = *(const f32x4*)(bc + kk + 4);
    f32x4 wv0 = *(const f32x4*)(wc + kk*2);
    f32x4 wv1 = *(const f32x4*)(wc + kk*2 + 4);
    f32x4 wv2 = *(const f32x4*)(wc + kk*2 + 8);
    f32x4 wv3 = *(const f32x4*)(wc + kk*2 + 12);
    bf16x8 g;
    g[0] = (bf16_t)fmaxf(fmaf(wv0.x, xrw, fmaf(wv0.y, yv, cA.x)), 0.f);
    g[1] = (bf16_t)fmaxf(fmaf(wv0.z, xrw, fmaf(wv0.w, yv, cA.y)), 0.f);
    g[2] = (bf16_t)fmaxf(fmaf(wv1.x, xrw, fmaf(wv1.y, yv, cA.z)), 0.f);
    g[3] = (bf16_t)fmaxf(fmaf(wv1.z, xrw, fmaf(wv1.w, yv, cA.w)), 0.f);
    g[4] = (bf16_t)fmaxf(fmaf(wv2.x, xrw, fmaf(wv2.y, yv, cB.x)), 0.f);
    g[5] = (bf16_t)fmaxf(fmaf(wv2.z, xrw, fmaf(wv2.w, yv, cB.y)), 0.f);
    g[6] = (bf16_t)fmaxf(fmaf(wv3.x, xrw, fmaf(wv3.y, yv, cB.z)), 0.f);
    g[7] = (bf16_t)fmaxf(fmaf(wv3.z, xrw, fmaf(wv3.w, yv, cB.w)), 0.f);

    bf16_t* stg = sStg + (ks & 1)*2048;          // 2 x 4 KB buffers
    *(bf16x8*)(stg + ((w << 6) + L)*8) = g;
    __syncthreads();                              // staging visible to all

#pragma unroll
    for (int mt = 0; mt < 4; ++mt) {
      bf16x8 af = *(const bf16x8*)(stg + ((mt << 6) + L)*8);
#pragma unroll
      for (int n = 0; n < 4; ++n)
        acc1[mt][n] = __builtin_amdgcn_mfma_f32_16x16x32_bf16(Bc[n], af, acc1[mt][n], 0, 0, 0);
    }
    if (ks + 1 < NKS) {
#pragma unroll
      for (int n = 0; n < 4; ++n) Bc[n] = Bn[n];
    }
  }
}

// ---------------------------------------------------------------------------
// Fused MLP. One WG = (m = bid>>8, 64-row grid tile = bid&255); m-major so all
// concurrent WGs share 2-3 m's -> packed weights L2-resident per XCD.
// L1 runs only the COMPACTED active channels (nks = ceil(Kc/32) K-chunks,
// static trip count via switch, LDS-shared A-frags); linear channels enter via
// the rank-1 fold F0 + Fx*x + Fy*y in the epilogue. MFMA operands swapped
// (B,A) -> D = C^T. Frag layouts (A and B identical): row/col = lane&15,
// k = (lane>>4)*8+j;  C/D: col = lane&15, row = quad*4+p.
// NOTE: (256,3) is load-bearing — (256,4) caps unified VGPR at 128 and spills
// the accumulators to scratch (round-3: WRITE_SIZE 3 MB -> 52 MB, VGPR 84->64).
// ---------------------------------------------------------------------------
__global__ __launch_bounds__(256, 3) void fused_mlp_k(
    const float* __restrict__ basec, const float* __restrict__ wxyc,
    const float* __restrict__ F, const int* __restrict__ Kc,
    const bf16_t* __restrict__ W1p, const bf16_t* __restrict__ W2p,
    const bf16_t* __restrict__ W3p,
    const float* __restrict__ b1, const float* __restrict__ b2,
    const float* __restrict__ b3, float* __restrict__ out)
{
  __shared__ __align__(16) bf16_t sA1[64*264];  // 33792 B; head doubles as L1
                                                // A-staging; reused as h2 later

  const int bid  = blockIdx.x;
  const int m    = bid >> 8;            // m-major: L2-resident weights
  const int tile = bid & 255;
  const int g0   = tile * 64;

  const int tid  = threadIdx.x;
  const int w    = tid >> 6, L = tid & 63;
  const int quad = L >> 4, lrow = L & 15;

  const float step = 2.0f / 127.0f;
  const float yv  = -1.0f + (float)(tile >> 1) * step;
  const float xv0 = -1.0f + (float)(((tile & 1) << 6) + lrow) * step;  // mt=0 row
  const float xrw = xv0 + (float)(w*16)*step;   // this wave's generated row

  const float* bc = basec + m*S0;
  const float* wc = wxyc + m*(S0*2);
  const int nks = (Kc[m] + 31) >> 5;    // compacted K-chunks (~10 of 16)

  f32x4 zero = {0.f, 0.f, 0.f, 0.f};
  f32x4 acc1[4][4];
#pragma unroll
  for (int a = 0; a < 4; ++a)
#pragma unroll
    for (int b = 0; b < 4; ++b) acc1[a][b] = zero;

  // ---------------- Layer 1: static-trip compacted K-loop ----------------
  const bf16_t* bp1 = W1p + (((size_t)(m*16)*16 + w*4)*64 + L)*8;
#define L1_CASE(NN) case NN: l1_compute<NN>(bp1, bc, wc, sA1, w, L, quad, yv, xrw, acc1); break;
  switch (nks) {
    L1_CASE(16) L1_CASE(15) L1_CASE(14) L1_CASE(13)
    L1_CASE(12) L1_CASE(11) L1_CASE(10) L1_CASE(9)
    L1_CASE(8)  L1_CASE(7)  L1_CASE(6)  L1_CASE(5)
    L1_CASE(4)  L1_CASE(3)  L1_CASE(2)  L1_CASE(1)
    default: break;   // nks == 0: all channels dead/linear, acc stays 0
  }
#undef L1_CASE
  __syncthreads();   // staging reads done before epilogue overwrites sA1

  // L1 epilogue: add bias + linear-channel fold (F0 + Fx*x + Fy*y), relu,
  // D^T -> thread holds 4 contiguous cols -> packed b64 stores
#pragma unroll
  for (int nb = 0; nb < 4; ++nb) {
    const int col = w*64 + nb*16 + quad*4;
    f32x4 bb = *(const f32x4*)(b1 + m*S1 + col);
    float cterm[4], fx[4];
#pragma unroll
    for (int p = 0; p < 4; ++p) {
      f32x4 Fv = *(const f32x4*)(F + ((size_t)m*S1 + col + p)*4);
      cterm[p] = fmaf(Fv.z, yv, bb[p] + Fv.x);   // b1 + F0 + Fy*y
      fx[p] = Fv.y;
    }
#pragma unroll
    for (int mt = 0; mt < 4; ++mt) {
      const int row = mt*16 + lrow;
      const float xr = xv0 + (float)(mt*16)*step;
      bf16x4 v;
#pragma unroll
      for (int p = 0; p < 4; ++p)
        v[p] = (bf16_t)fmaxf(acc1[mt][nb][p] + fmaf(fx[p], xr, cterm[p]), 0.f);
      *(bf16x4*)(&sA1[row*264 + col]) = v;
    }
  }
  __syncthreads();

  // ---------------- Layer 2: K=256, 8 chunks, barrier-free loop ----------------
  f32x4 acc2[4][2];
#pragma unroll
  for (int a = 0; a < 4; ++a) { acc2[a][0] = zero; acc2[a][1] = zero; }
  const bf16_t* bp2 = W2p + (((size_t)(m*8)*8 + w*2)*64 + L)*8;
#pragma unroll 2
  for (int ks = 0; ks < 8; ++ks) {
    const int k2 = ks*32 + quad*8;
    bf16x8 af[4];
#pragma unroll
    for (int mt = 0; mt < 4; ++mt)
      af[mt] = *(const bf16x8*)(&sA1[(mt*16 + lrow)*264 + k2]);
    bf16x8 b0f = *(const bf16x8*)(bp2 + (size_t)ks*4096);
    bf16x8 b1f = *(const bf16x8*)(bp2 + (size_t)ks*4096 + 512);
#pragma unroll
    for (int mt = 0; mt < 4; ++mt)
      acc2[mt][0] = __builtin_amdgcn_mfma_f32_16x16x32_bf16(b0f, af[mt], acc2[mt][0], 0, 0, 0);
#pragma unroll
    for (int mt = 0; mt < 4; ++mt)
      acc2[mt][1] = __builtin_amdgcn_mfma_f32_16x16x32_bf16(b1f, af[mt], acc2[mt][1], 0, 0, 0);
  }
  __syncthreads();   // all sA1 reads done before aliased h2 writes

  // L2 epilogue: h2 -> sH2 [64][136], packed b64 stores
  bf16_t* sH2 = sA1;
#pragma unroll
  for (int nb = 0; nb < 2; ++nb) {
    const int col = w*32 + nb*16 + quad*4;
    f32x4 bb = *(const f32x4*)(b2 + m*S2 + col);
#pragma unroll
    for (int mt = 0; mt < 4; ++mt) {
      const int row = mt*16 + lrow;
      bf16x4 v;
#pragma unroll
      for (int p = 0; p < 4; ++p)
        v[p] = (bf16_t)fmaxf(acc2[mt][nb][p] + bb[p], 0.f);
      *(bf16x4*)(&sH2[row*136 + col]) = v;
    }
  }
  __syncthreads();

  // ---------------- Layer 3: K=128, N padded to 16 ----------------
  f32x4 acc3 = zero;
#pragma unroll
  for (int ks = 0; ks < 4; ++ks) {
    bf16x8 af  = *(const bf16x8*)(&sH2[(w*16 + lrow)*136 + ks*32 + quad*8]);
    bf16x8 bfr = *(const bf16x8*)(W3p + (((size_t)m*4 + ks)*64 + L)*8);
    acc3 = __builtin_amdgcn_mfma_f32_16x16x32_bf16(bfr, af, acc3, 0, 0, 0);
  }
  if (quad == 0) {   // thread holds channels p=0..3 for grid row w*16+lrow
    const size_t o = ((size_t)m*GPTS + g0 + w*16 + lrow)*3;
    out[o + 0] = tanh_fast(acc3[0] + b3[m*3 + 0]);
    out[o + 1] = tanh_fast(acc3[1] + b3[m*3 + 1]);
    out[o + 2] = tanh_fast(acc3[2] + b3[m*3 + 2]);
  }
}

// ---------------------------------------------------------------------------
extern "C" void kernel_launch(void* const* d_in, const int* in_sizes, int n_in,
                              void* d_out, int out_size, void* d_ws, size_t ws_size,
                              hipStream_t stream) {
  const float* x0  = (const float*)d_in[0];
  const float* W0a = (const float*)d_in[1];
  const float* b0a = (const float*)d_in[2];
  const float* W0b = (const float*)d_in[3];
  const float* b0b = (const float*)d_in[4];
  const float* W1  = (const float*)d_in[5];
  const float* b1  = (const float*)d_in[6];
  const float* W2  = (const float*)d_in[7];
  const float* b2  = (const float*)d_in[8];
  const float* W3  = (const float*)d_in[9];
  const float* b3  = (const float*)d_in[10];

  char* ws = (char*)d_ws;
  float*  base  = (float*)(ws + WS_BASE);
  bf16_t* W1p   = (bf16_t*)(ws + WS_W1P);
  bf16_t* W2p   = (bf16_t*)(ws + WS_W2P);
  bf16_t* W3p   = (bf16_t*)(ws + WS_W3P);
  float*  basec = (float*)(ws + WS_BASEC);
  float*  wxyc  = (float*)(ws + WS_WXYC);
  int*    idx   = (int*)(ws + WS_IDX);
  int*    lin   = (int*)(ws + WS_LIN);
  float*  F     = (float*)(ws + WS_F);
  int*    Kc    = (int*)(ws + WS_CNT);
  int*    nlin  = (int*)(ws + WS_CNT + 64);
  float*  out   = (float*)d_out;

  prep_a<<<2368, 256, 0, stream>>>(x0, W0a, b0a, b0b, W2, W3, base, W2p, W3p);
  classify_k<<<16, 256, 0, stream>>>(base, W0b, basec, wxyc, idx, lin, Kc, nlin, F);
  prep_b<<<1280, 256, 0, stream>>>(W1, base, W0b, idx, lin, Kc, nlin, W1p, F);
  fused_mlp_k<<<4096, 256, 0, stream>>>(basec, wxyc, F, Kc, W1p, W2p, W3p, b1, b2, b3, out);
}